// Round 7
// baseline (14471.233 us; speedup 1.0000x reference)
//
#include <hip/hip_runtime.h>
#include <math.h>

#define BB 256   // batch
#define TT 128   // time steps
#define DD 256   // input dim
#define UU 512   // units
#define G5 (5 * UU)   // 2560
#define G4 (4 * UU)   // 2048 (packed width for rk and tk)
#define NBLK 512      // 16 bm-groups x 32 bn-blocks, 2 blocks/CU
#define GBLK 32       // blocks per barrier group (same bm)
#define BMR 16        // batch rows per block

__device__ __forceinline__ float hsig(float x) {
    return fminf(fmaxf(0.2f * x + 0.5f, 0.0f), 1.0f);
}

// Cross-block data discipline: EVERY access to hT/h1aT/h1bT/prl/xg goes
// through SYSTEM-scope relaxed atomics (sc0+sc1: bypass vL1 AND the
// non-coherent per-XCD L2, serve/land at the memory-side LLC). R4 showed
// agent scope (sc1 only) allows vL1 hits -> stale reads. System-relaxed
// ops emit NO cache-maintenance instructions, so weights stay L2-resident
// across all 384 phases.
__device__ __forceinline__ void st_sys(float* p, float v) {
    __hip_atomic_store(p, v, __ATOMIC_RELAXED, __HIP_MEMORY_SCOPE_SYSTEM);
}
__device__ __forceinline__ float ld_sys(const float* p) {
    return __hip_atomic_load(p, __ATOMIC_RELAXED, __HIP_MEMORY_SCOPE_SYSTEM);
}

// ---------------------------------------------------------------------------
// Pack weights into gate-interleaved layout: col = u*4 + g   (verified layout)
// ---------------------------------------------------------------------------
__global__ __launch_bounds__(256) void pack_weights(
    const float* __restrict__ rk, const float* __restrict__ tk,
    float* __restrict__ rkp, float* __restrict__ tkp0, float* __restrict__ tkp1)
{
    int idx = blockIdx.x * 256 + threadIdx.x;   // 0 .. 512*2048
    int k = idx >> 11;
    int c = idx & 2047;
    int u = c >> 2;
    int g = c & 3;
    rkp[idx] = rk[k * G4 + g * UU + u];
    float t0 = 0.f, t1 = 0.f;
    if (g < 3) {
        t0 = tk[(size_t)k * (3 * UU) + g * UU + u];
        t1 = tk[(size_t)(UU + k) * (3 * UU) + g * UU + u];
    }
    tkp0[idx] = t0;
    tkp1[idx] = t1;
}

// h state kept transposed: hT[u][b]  (u-major) so GEMM A-staging is coalesced
__global__ __launch_bounds__(256) void init_hT(
    const float* __restrict__ h0, float* __restrict__ hT)
{
    int idx = blockIdx.x * 256 + threadIdx.x;   // 0 .. 131071
    int u = idx >> 8;
    int b = idx & 255;
    hT[idx] = h0[(size_t)b * UU + u];
}

// ---------------------------------------------------------------------------
// Group-local monotonic barrier (32 blocks sharing the same bm).
// RELEASE: after __syncthreads drains every wave's vmcnt, thread0 issues
// fence(RELEASE,"agent") -> s_waitcnt + buffer_wbl2: pushes ALL the block's
// prior writes (incl. in-flight write-through sc1 stores past L2) to the
// LLC coherence point BEFORE the counter bump becomes visible. The L2 is
// nearly clean (state/xg stores are write-through; only `out` is dirty), so
// the wbl2 walk is cheap — unlike R2 where plain stores made it a 1.5 GB/
// dispatch disaster. R5/R6 relied on vmcnt(0) alone as the release: store
// *completion* != LLC *arrival* for sc1 stores; R6's 2x occupancy widened
// that window -> marginal stale reads (absmax 0.025).
// ACQUIRE: none needed for data (sys-loads read LLC directly); workgroup
// fence is compiler-ordering only. No buffer_inv anywhere -> weights stay
// L2-resident.
// ---------------------------------------------------------------------------
__device__ __forceinline__ void gbar(unsigned* cnt, unsigned& phase) {
    __syncthreads();
    if (threadIdx.x == 0) {
        phase += GBLK;
        __builtin_amdgcn_fence(__ATOMIC_RELEASE, "agent");   // waitcnt + wbl2
        __hip_atomic_fetch_add(cnt, 1u, __ATOMIC_RELAXED, __HIP_MEMORY_SCOPE_AGENT);
        while ((int)(__hip_atomic_load(cnt, __ATOMIC_RELAXED, __HIP_MEMORY_SCOPE_AGENT) - phase) < 0)
            __builtin_amdgcn_s_sleep(2);
        __builtin_amdgcn_fence(__ATOMIC_ACQUIRE, "workgroup");   // waitcnt only
    }
    __syncthreads();
    __builtin_amdgcn_sched_barrier(0);
}

// ---------------------------------------------------------------------------
// RT GEMM: C(16 x 64packed) = A_T[bm..bm+16]^T @ Wp[:, bn..bn+64], K=512.
// 4 waves k-split (wave kg owns kk in [kg*16, kg*16+16) of each BK=64 tile);
// per-lane 2x8 microtile (rows r8*2..+1, cols c8*8..+7); cross-wave LDS sum.
// After reduction (kg,lane) owns row bm + r8*2 + (kg&1), gate-quad
// u = bn/4 + c8*2 + (kg>>1)  ->  s[0..3].
// A = cross-block state -> scalar sys loads (R5-proven primitive);
// W = plain loads (L2-resident). Register double-buffered staging.
// ---------------------------------------------------------------------------
__device__ __forceinline__ void rt_gemm(
    const float* __restrict__ AT,   // [512][256] k-major (transposed activ.)
    const float* __restrict__ Wp,   // [512][2048] packed
    int bm, int bn, int tid,
    float (* __restrict__ As)[20], float (* __restrict__ Ws)[80],
    float* __restrict__ RedF,
    float* __restrict__ s, int& row_out, int& u_out)
{
    const int lane = tid & 63;
    const int kg = tid >> 6;          // wave = k-split group
    const int r8 = lane & 7;
    const int c8 = lane >> 3;
    const int akr = tid >> 2;         // A staging: k-row 0..63
    const int amc = (tid & 3) * 4;    //            m-col 0,4,8,12
    const int wwr = tid >> 4;         // W staging: k-row 0..15 (+16/32/48)
    const int wwc = (tid & 15) * 4;   //            n-col

    const float* ap = AT + (size_t)akr * BB + bm + amc;
    const float* wp = Wp + (size_t)wwr * G4 + bn + wwc;

    float a[4];
#pragma unroll
    for (int j = 0; j < 4; ++j) a[j] = ld_sys(ap + j);
    float4 w0 = *(const float4*)wp;
    float4 w1 = *(const float4*)(wp + 16 * G4);
    float4 w2 = *(const float4*)(wp + 32 * G4);
    float4 w3 = *(const float4*)(wp + 48 * G4);

    float acc[2][8];
#pragma unroll
    for (int r = 0; r < 2; ++r)
#pragma unroll
        for (int j = 0; j < 8; ++j) acc[r][j] = 0.f;

#pragma unroll 1
    for (int tile = 0; tile < 8; ++tile) {
        __syncthreads();              // prev tile reads / prev phase LDS done
        float4 av4 = {a[0], a[1], a[2], a[3]};
        *(float4*)&As[akr][amc] = av4;
        *(float4*)&Ws[wwr][wwc] = w0;
        *(float4*)&Ws[wwr + 16][wwc] = w1;
        *(float4*)&Ws[wwr + 32][wwc] = w2;
        *(float4*)&Ws[wwr + 48][wwc] = w3;
        if (tile < 7) {               // prefetch next tile into regs
            ap += 64 * BB;
            wp += 64 * G4;
#pragma unroll
            for (int j = 0; j < 4; ++j) a[j] = ld_sys(ap + j);
            w0 = *(const float4*)wp;
            w1 = *(const float4*)(wp + 16 * G4);
            w2 = *(const float4*)(wp + 32 * G4);
            w3 = *(const float4*)(wp + 48 * G4);
        }
        __syncthreads();              // staged tile visible
        const int kb = kg * 16;
#pragma unroll
        for (int q = 0; q < 16; ++q) {
            float2 av = *(const float2*)&As[kb + q][r8 * 2];
            float4 wv0 = *(const float4*)&Ws[kb + q][c8 * 8];
            float4 wv1 = *(const float4*)&Ws[kb + q][c8 * 8 + 4];
            float wv[8] = {wv0.x, wv0.y, wv0.z, wv0.w, wv1.x, wv1.y, wv1.z, wv1.w};
#pragma unroll
            for (int j = 0; j < 8; ++j) {
                acc[0][j] += av.x * wv[j];
                acc[1][j] += av.y * wv[j];
            }
        }
    }

    // cross-wave k reduction (lane fastest -> conflict-free)
#pragma unroll
    for (int r = 0; r < 2; ++r)
#pragma unroll
        for (int j = 0; j < 8; ++j)
            RedF[(kg * 16 + r * 8 + j) * 64 + lane] = acc[r][j];
    __syncthreads();
    const int rr = kg & 1;
    const int jb = (kg >> 1) * 4;
#pragma unroll
    for (int jj = 0; jj < 4; ++jj)
        s[jj] = RedF[(rr * 8 + jb + jj) * 64 + lane]
              + RedF[(16 + rr * 8 + jb + jj) * 64 + lane]
              + RedF[(32 + rr * 8 + jb + jj) * 64 + lane]
              + RedF[(48 + rr * 8 + jb + jj) * 64 + lane];
    row_out = bm + r8 * 2 + rr;
    u_out = (bn >> 2) + c8 * 2 + (kg >> 1);
}

// ---------------------------------------------------------------------------
// xg phase: xg[t][m][n] = x[m][t][:] @ Wxg + bias0, M=16 rows, N=80 cols.
// Per-lane 2x10 microtile (cols c8*8..+7 and 64+c8*2..+1). Wave kg owns row
// r8*2+(kg&1) and col-half (kg>>1)*5..+5 after reduction.
// x/Wxg are kernel inputs -> plain loads (L2); output -> st_sys.
// ---------------------------------------------------------------------------
__device__ __forceinline__ void xg_phase(
    const float* __restrict__ x, const float* __restrict__ Wxg,
    const float* __restrict__ bias0, float* __restrict__ xgdst, int t,
    int bm, int bnx, int tid,
    float (* __restrict__ As)[20], float (* __restrict__ Ws)[80],
    float* __restrict__ RedF)
{
    const int lane = tid & 63;
    const int kg = tid >> 6;
    const int r8 = lane & 7;
    const int c8 = lane >> 3;
    const int xbr = tid >> 4;            // 0..15 batch row
    const int xdc = (tid & 15) * 4;      // 0..60 d base

    float acc[2][10];
#pragma unroll
    for (int r = 0; r < 2; ++r)
#pragma unroll
        for (int c = 0; c < 10; ++c) acc[r][c] = 0.f;

    const float* xrow = x + ((size_t)(bm + xbr) * TT + t) * DD;

#pragma unroll 1
    for (int tile = 0; tile < 4; ++tile) {
        const int k0 = tile * 64;
        float4 xa = *(const float4*)(xrow + k0 + xdc);
        float4 wv[5];
#pragma unroll
        for (int l = 0; l < 5; ++l) {
            int idx = tid + l * 256;         // 0..1279 covers 64x80 / 4
            int wrow = idx / 20;
            int wcol = (idx % 20) * 4;
            wv[l] = *(const float4*)(Wxg + (size_t)(k0 + wrow) * G5 + bnx + wcol);
        }
        __syncthreads();
        As[xdc + 0][xbr] = xa.x; As[xdc + 1][xbr] = xa.y;
        As[xdc + 2][xbr] = xa.z; As[xdc + 3][xbr] = xa.w;
#pragma unroll
        for (int l = 0; l < 5; ++l) {
            int idx = tid + l * 256;
            int wrow = idx / 20;
            int wcol = (idx % 20) * 4;
            *(float4*)&Ws[wrow][wcol] = wv[l];
        }
        __syncthreads();
        const int kb = kg * 16;
#pragma unroll
        for (int q = 0; q < 16; ++q) {
            float2 av = *(const float2*)&As[kb + q][r8 * 2];
            float4 wv0 = *(const float4*)&Ws[kb + q][c8 * 8];
            float4 wv1 = *(const float4*)&Ws[kb + q][c8 * 8 + 4];
            float2 wv2 = *(const float2*)&Ws[kb + q][64 + c8 * 2];
            float wvv[10] = {wv0.x, wv0.y, wv0.z, wv0.w,
                             wv1.x, wv1.y, wv1.z, wv1.w, wv2.x, wv2.y};
#pragma unroll
            for (int c = 0; c < 10; ++c) {
                acc[0][c] += av.x * wvv[c];
                acc[1][c] += av.y * wvv[c];
            }
        }
    }

#pragma unroll
    for (int r = 0; r < 2; ++r)
#pragma unroll
        for (int c = 0; c < 10; ++c)
            RedF[(kg * 20 + r * 10 + c) * 64 + lane] = acc[r][c];
    __syncthreads();
    const int rr = kg & 1;
    const int cb = (kg >> 1) * 5;
    const int row = bm + r8 * 2 + rr;
#pragma unroll
    for (int cc = 0; cc < 5; ++cc) {
        int c = cb + cc;
        float sv = RedF[(rr * 10 + c) * 64 + lane]
                 + RedF[(20 + rr * 10 + c) * 64 + lane]
                 + RedF[(40 + rr * 10 + c) * 64 + lane]
                 + RedF[(60 + rr * 10 + c) * 64 + lane];
        int n = bnx + (c < 8 ? c8 * 8 + c : 64 + c8 * 2 + (c - 8));
        st_sys(&xgdst[(size_t)row * G5 + n], sv + bias0[n]);
    }
}

// ---------------------------------------------------------------------------
// Persistent scan kernel: 512 blocks (2/CU) x 256 threads, plain launch.
// Per step: R -> gbar -> T0 (+xg(t+1)) -> gbar -> T1(final) -> gbar.
// Barriers are GROUP-LOCAL (32 blocks sharing bm). LDS 45KB/block.
// ---------------------------------------------------------------------------
__global__ __launch_bounds__(256, 2) void scan_all(
    const float* __restrict__ x,
    const float* __restrict__ Wxg,
    const float* __restrict__ rkp,
    const float* __restrict__ tkp0,
    const float* __restrict__ tkp1,
    const float* __restrict__ bias,
    const float* __restrict__ tb,
    float* hT, float* h1aT, float* h1bT, float* prl,
    float* xg0, float* xg1, float* out, unsigned* bar)
{
    __shared__ float As[64][20];      // [k][m], pad 16->20 (float4-aligned)
    __shared__ float Ws[64][80];      // [k][n] (RT uses 64 cols, XG 80)
    __shared__ float RedF[5120];      // cross-wave reduction scratch (20 KB)

    const int tid = threadIdx.x;
    const int bid = blockIdx.x;
    const int bm = (bid >> 5) * BMR;
    const int bn = (bid & 31) * 64;
    const int bnx = (bid & 31) * 80;

    unsigned* cnt = bar + (bid >> 5) * 32;   // group counter, 128B apart
    unsigned phase = 0;

    const float* bias0 = bias;
    const float* bias1 = bias + G5;
    const float* tb0 = tb;
    const float* tb1 = tb + 3 * UU;

    // xg for t=0
    xg_phase(x, Wxg, bias0, xg0, 0, bm, bnx, tid, As, Ws, RedF);
    gbar(cnt, phase);

    float* xgc = xg0;
    float* xgn = xg1;

    for (int t = 0; t < TT; ++t) {
        // ---- R: hg = h @ rkp ; gates -> h1a, pre_l ----
        {
            float s[4]; int row, u;
            rt_gemm(hT, rkp, bm, bn, tid, As, Ws, RedF, s, row, u);
            const float* xr_ = xgc + (size_t)row * G5;
            float z  = hsig(ld_sys(xr_ + u) + s[0] + bias1[u]);
            float r  = hsig(ld_sys(xr_ + UU + u) + s[1] + bias1[UU + u]);
            float hh = tanhf(ld_sys(xr_ + 2 * UU + u) + r * (s[2] + bias1[2 * UU + u]));
            float hold = ld_sys(&hT[(size_t)u * BB + row]);
            st_sys(&h1aT[(size_t)u * BB + row], z * hold + (1.f - z) * hh);
            st_sys(&prl[(size_t)row * UU + u],
                   ld_sys(xr_ + 3 * UU + u) + s[3] + bias1[3 * UU + u]);
        }
        gbar(cnt, phase);

        // ---- T0: tg = h1a @ tkp0 ; gates -> h1b ; plus xg(t+1) ----
        {
            float s[4]; int row, u;
            rt_gemm(h1aT, tkp0, bm, bn, tid, As, Ws, RedF, s, row, u);
            float zt = hsig(s[0] + tb0[u]);
            float rt = hsig(s[1] + tb0[UU + u]);
            float ht = tanhf(rt * (s[2] + tb0[2 * UU + u]));
            float h1v = ld_sys(&h1aT[(size_t)u * BB + row]);
            st_sys(&h1bT[(size_t)u * BB + row], zt * h1v + (1.f - zt) * ht);
        }
        if (t + 1 < TT)
            xg_phase(x, Wxg, bias0, xgn, t + 1, bm, bnx, tid, As, Ws, RedF);
        gbar(cnt, phase);

        // ---- T1 (final): tg = h1b @ tkp1 ; gates + output gate -> h, out ----
        {
            float s[4]; int row, u;
            rt_gemm(h1bT, tkp1, bm, bn, tid, As, Ws, RedF, s, row, u);
            float zt = hsig(s[0] + tb1[u]);
            float rt = hsig(s[1] + tb1[UU + u]);
            float ht = tanhf(rt * (s[2] + tb1[2 * UU + u]));
            float h1v = ld_sys(&h1bT[(size_t)u * BB + row]);
            float h2 = zt * h1v + (1.f - zt) * ht;
            float l = hsig(ld_sys(&prl[(size_t)row * UU + u]));
            float xl2 = ld_sys(&xgc[(size_t)row * G5 + 4 * UU + u]);
            float ho = l * h2 + (1.f - l) * tanhf(xl2);
            st_sys(&hT[(size_t)u * BB + row], ho);
            out[((size_t)row * TT + t) * UU + u] = ho;   // host-read only
        }
        gbar(cnt, phase);

        float* tmp = xgc; xgc = xgn; xgn = tmp;
    }
}

extern "C" void kernel_launch(void* const* d_in, const int* in_sizes, int n_in,
                              void* d_out, int out_size, void* d_ws, size_t ws_size,
                              hipStream_t stream) {
    const float* x      = (const float*)d_in[0];  // (B,T,D)
    const float* h0     = (const float*)d_in[1];  // (B,U)
    const float* kernel = (const float*)d_in[2];  // (D,5U)
    const float* rk     = (const float*)d_in[3];  // (U,4U)
    const float* tk     = (const float*)d_in[4];  // (2,U,3U)
    const float* bias   = (const float*)d_in[5];  // (2,5U)
    const float* tb     = (const float*)d_in[6];  // (2,3U)
    float* out = (float*)d_out;

    // workspace layout (floats); barrier counters occupy first 2048 B
    unsigned* bar = (unsigned*)d_ws;
    float* base = (float*)d_ws + 512;
    float* rkp  = base;                               // 512*2048
    float* tkp0 = rkp  + (size_t)UU * G4;             // 512*2048
    float* tkp1 = tkp0 + (size_t)UU * G4;             // 512*2048
    float* hT   = tkp1 + (size_t)UU * G4;             // U*B (transposed state)
    float* h1aT = hT   + (size_t)BB * UU;
    float* h1bT = h1aT + (size_t)BB * UU;
    float* prl  = h1bT + (size_t)BB * UU;
    float* xg0  = prl  + (size_t)BB * UU;             // B*5U
    float* xg1  = xg0  + (size_t)BB * G5;             // B*5U

    hipMemsetAsync(d_ws, 0, 2048, stream);   // zero barrier counters
    pack_weights<<<dim3((UU * G4) / 256), dim3(256), 0, stream>>>(rk, tk, rkp, tkp0, tkp1);
    init_hT<<<dim3((BB * UU) / 256), dim3(256), 0, stream>>>(h0, hT);

    // Plain launch (graph-capture safe). Residency by capacity: 45KB LDS and
    // <=256 VGPR/wave -> 2 blocks/CU, 512 blocks <= 256 CUs * 2.
    scan_all<<<dim3(NBLK), dim3(256), 0, stream>>>(
        x, kernel, rkp, tkp0, tkp1, bias, tb,
        hT, h1aT, h1bT, prl, xg0, xg1, out, bar);
}

// Round 8
// 7806.001 us; speedup vs baseline: 1.8539x; 1.8539x over previous
//
#include <hip/hip_runtime.h>
#include <math.h>

#define BB 256   // batch
#define TT 128   // time steps
#define DD 256   // input dim
#define UU 512   // units
#define G5 (5 * UU)   // 2560
#define G4 (4 * UU)   // 2048 (packed width for rk and tk)
#define NBLK 256      // 8 bm-groups x 32 bn-blocks, 1 block/CU (R5-proven)
#define GBLK 32       // blocks per barrier group (same bm)
#define BMR 32        // batch rows per block

__device__ __forceinline__ float hsig(float x) {
    return fminf(fmaxf(0.2f * x + 0.5f, 0.0f), 1.0f);
}

// Cross-block data discipline (R5-proven): EVERY access to hT/h1aT/h1bT/prl/
// xg goes through SYSTEM-scope relaxed atomics (sc0+sc1: bypass vL1 AND the
// non-coherent per-XCD L2; serve/land at the memory-side LLC). No cache-
// maintenance instructions anywhere -> weights stay L2-resident across all
// 384 phases. (R2: wbl2+inv ACQ_REL barrier = 18.8ms; R3: inv-acquire =
// 8.5ms but 16MB/step weight refetch; R7: wbl2-release = 14.5ms. R5's
// zero-maintenance scheme = 9.5ms and passed.)
__device__ __forceinline__ void st_sys(float* p, float v) {
    __hip_atomic_store(p, v, __ATOMIC_RELAXED, __HIP_MEMORY_SCOPE_SYSTEM);
}
__device__ __forceinline__ float ld_sys(const float* p) {
    return __hip_atomic_load(p, __ATOMIC_RELAXED, __HIP_MEMORY_SCOPE_SYSTEM);
}

// ---------------------------------------------------------------------------
// Pack weights into gate-interleaved layout: col = u*4 + g   (verified layout)
// ---------------------------------------------------------------------------
__global__ __launch_bounds__(256) void pack_weights(
    const float* __restrict__ rk, const float* __restrict__ tk,
    float* __restrict__ rkp, float* __restrict__ tkp0, float* __restrict__ tkp1)
{
    int idx = blockIdx.x * 256 + threadIdx.x;   // 0 .. 512*2048
    int k = idx >> 11;
    int c = idx & 2047;
    int u = c >> 2;
    int g = c & 3;
    rkp[idx] = rk[k * G4 + g * UU + u];
    float t0 = 0.f, t1 = 0.f;
    if (g < 3) {
        t0 = tk[(size_t)k * (3 * UU) + g * UU + u];
        t1 = tk[(size_t)(UU + k) * (3 * UU) + g * UU + u];
    }
    tkp0[idx] = t0;
    tkp1[idx] = t1;
}

// h state kept transposed: hT[u][b]  (u-major) so GEMM A-staging is coalesced
__global__ __launch_bounds__(256) void init_hT(
    const float* __restrict__ h0, float* __restrict__ hT)
{
    int idx = blockIdx.x * 256 + threadIdx.x;   // 0 .. 131071
    int u = idx >> 8;
    int b = idx & 255;
    hT[idx] = h0[(size_t)b * UU + u];
}

// ---------------------------------------------------------------------------
// Group-local monotonic barrier (32 blocks sharing the same bm) — byte-
// identical to the R5-passing sequence. __syncthreads drains every wave's
// vmcnt (sys stores complete) before thread0's RMW; waiters' sys-loads read
// the LLC directly. No cache-maintenance ops.
// ---------------------------------------------------------------------------
__device__ __forceinline__ void gbar(unsigned* cnt, unsigned& phase) {
    __syncthreads();
    if (threadIdx.x == 0) {
        phase += GBLK;
        __hip_atomic_fetch_add(cnt, 1u, __ATOMIC_RELAXED, __HIP_MEMORY_SCOPE_AGENT);
        while ((int)(__hip_atomic_load(cnt, __ATOMIC_RELAXED, __HIP_MEMORY_SCOPE_AGENT) - phase) < 0)
            __builtin_amdgcn_s_sleep(2);
        __builtin_amdgcn_fence(__ATOMIC_ACQUIRE, "workgroup");   // waitcnt only
    }
    __syncthreads();
    __builtin_amdgcn_sched_barrier(0);
}

// ---------------------------------------------------------------------------
// RT GEMM, 512 threads / 8 waves: C(32 x 64packed) = A_T^T @ Wp, K=512.
// Wave wv = mh*4+kg? -> encoded wv = tid>>6, kg = wv&3 (k-split group),
// mh = wv>>2 (row half). Wave (kg,mh): k-rows [kg*16,kg*16+16) of each BK=64
// tile, rows mh*16 + r8*2..+1, cols c8*8..+7 -> per-lane acc[2][8].
// Cross-wave k-reduction via RedF (lane-fastest, conflict-free). After
// reduction (kg,mh,lane) owns row bm + mh*16 + r8*2 + (kg&1), gate-quad
// u = bn/4 + c8*2 + (kg>>1) -> s[0..3].  (Bijective: (mh,r8,kg&1) x
// (c8,kg>>1) = 32 rows x 16 u = 512 = thread count.)
// A = cross-block state -> scalar sys loads; W = plain loads (L2-resident).
// Register double-buffered staging (tile t+1 loads issued during tile t).
// ---------------------------------------------------------------------------
__device__ __forceinline__ void rt_gemm(
    const float* __restrict__ AT,   // [512][256] k-major (transposed activ.)
    const float* __restrict__ Wp,   // [512][2048] packed
    int bm, int bn, int tid,
    float (* __restrict__ As)[36], float (* __restrict__ Ws)[80],
    float* __restrict__ RedF,
    float* __restrict__ s, int& row_out, int& u_out)
{
    const int lane = tid & 63;
    const int wv  = tid >> 6;         // 0..7
    const int kg  = wv & 3;           // k-split group
    const int mh  = wv >> 2;          // row half
    const int r8 = lane & 7;
    const int c8 = lane >> 3;
    const int akr = tid >> 3;         // A staging: k-row 0..63
    const int amc = (tid & 7) * 4;    //            m-col 0..28
    const int wwr = tid >> 4;         // W staging: k-row 0..31 (+32)
    const int wwc = (tid & 15) * 4;   //            n-col

    const float* ap = AT + (size_t)akr * BB + bm + amc;
    const float* wp = Wp + (size_t)wwr * G4 + bn + wwc;

    float a[4];
#pragma unroll
    for (int j = 0; j < 4; ++j) a[j] = ld_sys(ap + j);
    float4 w0 = *(const float4*)wp;
    float4 w1 = *(const float4*)(wp + 32 * G4);

    float acc[2][8];
#pragma unroll
    for (int r = 0; r < 2; ++r)
#pragma unroll
        for (int j = 0; j < 8; ++j) acc[r][j] = 0.f;

#pragma unroll 1
    for (int tile = 0; tile < 8; ++tile) {
        __syncthreads();              // prev tile reads / prev phase LDS done
        float4 av4 = {a[0], a[1], a[2], a[3]};
        *(float4*)&As[akr][amc] = av4;
        *(float4*)&Ws[wwr][wwc] = w0;
        *(float4*)&Ws[wwr + 32][wwc] = w1;
        if (tile < 7) {               // prefetch next tile into regs
            ap += 64 * BB;
            wp += 64 * G4;
#pragma unroll
            for (int j = 0; j < 4; ++j) a[j] = ld_sys(ap + j);
            w0 = *(const float4*)wp;
            w1 = *(const float4*)(wp + 32 * G4);
        }
        __syncthreads();              // staged tile visible
        const int kb = kg * 16;
#pragma unroll
        for (int q = 0; q < 16; ++q) {
            float2 av = *(const float2*)&As[kb + q][mh * 16 + r8 * 2];
            float4 wv0 = *(const float4*)&Ws[kb + q][c8 * 8];
            float4 wv1 = *(const float4*)&Ws[kb + q][c8 * 8 + 4];
            float wvv[8] = {wv0.x, wv0.y, wv0.z, wv0.w, wv1.x, wv1.y, wv1.z, wv1.w};
#pragma unroll
            for (int j = 0; j < 8; ++j) {
                acc[0][j] += av.x * wvv[j];
                acc[1][j] += av.y * wvv[j];
            }
        }
    }

    // cross-wave k reduction (lane fastest -> conflict-free); 8*16*64 floats
#pragma unroll
    for (int r = 0; r < 2; ++r)
#pragma unroll
        for (int j = 0; j < 8; ++j)
            RedF[(wv * 16 + r * 8 + j) * 64 + lane] = acc[r][j];
    __syncthreads();
    const int rr = kg & 1;
    const int jb = (kg >> 1) * 4;
#pragma unroll
    for (int jj = 0; jj < 4; ++jj)
        s[jj] = RedF[((mh * 4 + 0) * 16 + rr * 8 + jb + jj) * 64 + lane]
              + RedF[((mh * 4 + 1) * 16 + rr * 8 + jb + jj) * 64 + lane]
              + RedF[((mh * 4 + 2) * 16 + rr * 8 + jb + jj) * 64 + lane]
              + RedF[((mh * 4 + 3) * 16 + rr * 8 + jb + jj) * 64 + lane];
    row_out = bm + mh * 16 + r8 * 2 + rr;
    u_out = (bn >> 2) + c8 * 2 + (kg >> 1);
}

// ---------------------------------------------------------------------------
// xg phase, 512 threads: xg[t][m][n] = x[m][t][:] @ Wxg + bias0,
// M=32 rows, N=80 cols, K=256. Wave (kg,mh) as in rt_gemm; per-lane
// acc[2][10] (cols c8*8..+7 and 64+c8*2..+1). After reduction wave (kg,mh)
// owns row mh*16+r8*2+(kg&1), col-half (kg>>1)*5..+5.
// x/Wxg are kernel inputs -> plain loads (L2); output -> st_sys.
// ---------------------------------------------------------------------------
__device__ __forceinline__ void xg_phase(
    const float* __restrict__ x, const float* __restrict__ Wxg,
    const float* __restrict__ bias0, float* __restrict__ xgdst, int t,
    int bm, int bnx, int tid,
    float (* __restrict__ As)[36], float (* __restrict__ Ws)[80],
    float* __restrict__ RedF)
{
    const int lane = tid & 63;
    const int wv  = tid >> 6;
    const int kg  = wv & 3;
    const int mh  = wv >> 2;
    const int r8 = lane & 7;
    const int c8 = lane >> 3;
    const int xbr = tid >> 4;            // 0..31 batch row
    const int xdc = (tid & 15) * 4;      // 0..60 d base

    float acc[2][10];
#pragma unroll
    for (int r = 0; r < 2; ++r)
#pragma unroll
        for (int c = 0; c < 10; ++c) acc[r][c] = 0.f;

    const float* xrow = x + ((size_t)(bm + xbr) * TT + t) * DD;

#pragma unroll 1
    for (int tile = 0; tile < 4; ++tile) {
        const int k0 = tile * 64;
        float4 xa = *(const float4*)(xrow + k0 + xdc);
        float2 wl[5];
        int wrow[5], wcol[5];
#pragma unroll
        for (int l = 0; l < 5; ++l) {
            int idx = tid + l * 512;         // 0..2559 covers 64x80 / 2
            wrow[l] = idx / 40;
            wcol[l] = (idx % 40) * 2;
            wl[l] = *(const float2*)(Wxg + (size_t)(k0 + wrow[l]) * G5 + bnx + wcol[l]);
        }
        __syncthreads();
        As[xdc + 0][xbr] = xa.x; As[xdc + 1][xbr] = xa.y;
        As[xdc + 2][xbr] = xa.z; As[xdc + 3][xbr] = xa.w;
#pragma unroll
        for (int l = 0; l < 5; ++l)
            *(float2*)&Ws[wrow[l]][wcol[l]] = wl[l];
        __syncthreads();
        const int kb = kg * 16;
#pragma unroll
        for (int q = 0; q < 16; ++q) {
            float2 av = *(const float2*)&As[kb + q][mh * 16 + r8 * 2];
            float4 wv0 = *(const float4*)&Ws[kb + q][c8 * 8];
            float4 wv1 = *(const float4*)&Ws[kb + q][c8 * 8 + 4];
            float2 wv2 = *(const float2*)&Ws[kb + q][64 + c8 * 2];
            float wvv[10] = {wv0.x, wv0.y, wv0.z, wv0.w,
                             wv1.x, wv1.y, wv1.z, wv1.w, wv2.x, wv2.y};
#pragma unroll
            for (int c = 0; c < 10; ++c) {
                acc[0][c] += av.x * wvv[c];
                acc[1][c] += av.y * wvv[c];
            }
        }
    }

#pragma unroll
    for (int r = 0; r < 2; ++r)
#pragma unroll
        for (int c = 0; c < 10; ++c)
            RedF[(wv * 20 + r * 10 + c) * 64 + lane] = acc[r][c];
    __syncthreads();
    const int rr = kg & 1;
    const int cb = (kg >> 1) * 5;
    const int row = bm + mh * 16 + r8 * 2 + rr;
#pragma unroll
    for (int cc = 0; cc < 5; ++cc) {
        int c = cb + cc;
        float sv = RedF[((mh * 4 + 0) * 20 + rr * 10 + c) * 64 + lane]
                 + RedF[((mh * 4 + 1) * 20 + rr * 10 + c) * 64 + lane]
                 + RedF[((mh * 4 + 2) * 20 + rr * 10 + c) * 64 + lane]
                 + RedF[((mh * 4 + 3) * 20 + rr * 10 + c) * 64 + lane];
        int n = bnx + (c < 8 ? c8 * 8 + c : 64 + c8 * 2 + (c - 8));
        st_sys(&xgdst[(size_t)row * G5 + n], sv + bias0[n]);
    }
}

// ---------------------------------------------------------------------------
// Persistent scan kernel: 256 blocks (1/CU) x 512 threads (8 waves = 2/SIMD),
// plain launch. Per step: R -> gbar -> T0 (+xg(t+1)) -> gbar -> T1 -> gbar.
// Barriers GROUP-LOCAL (32 blocks sharing bm). LDS ~69KB/block.
// ---------------------------------------------------------------------------
__global__ __launch_bounds__(512, 1) void scan_all(
    const float* __restrict__ x,
    const float* __restrict__ Wxg,
    const float* __restrict__ rkp,
    const float* __restrict__ tkp0,
    const float* __restrict__ tkp1,
    const float* __restrict__ bias,
    const float* __restrict__ tb,
    float* hT, float* h1aT, float* h1bT, float* prl,
    float* xg0, float* xg1, float* out, unsigned* bar)
{
    __shared__ float As[64][36];      // [k][m], pad 32->36 keeps b128 aligned
    __shared__ float Ws[64][80];      // [k][n] (RT uses 64 cols, XG 80)
    __shared__ float RedF[10240];     // cross-wave reduction scratch (40 KB)

    const int tid = threadIdx.x;
    const int bid = blockIdx.x;
    const int bm = (bid >> 5) * BMR;
    const int bn = (bid & 31) * 64;
    const int bnx = (bid & 31) * 80;

    unsigned* cnt = bar + (bid >> 5) * 32;   // group counter, 128B apart
    unsigned phase = 0;

    const float* bias0 = bias;
    const float* bias1 = bias + G5;
    const float* tb0 = tb;
    const float* tb1 = tb + 3 * UU;

    // xg for t=0
    xg_phase(x, Wxg, bias0, xg0, 0, bm, bnx, tid, As, Ws, RedF);
    gbar(cnt, phase);

    float* xgc = xg0;
    float* xgn = xg1;

    for (int t = 0; t < TT; ++t) {
        // ---- R: hg = h @ rkp ; gates -> h1a, pre_l ----
        {
            float s[4]; int row, u;
            rt_gemm(hT, rkp, bm, bn, tid, As, Ws, RedF, s, row, u);
            const float* xr_ = xgc + (size_t)row * G5;
            float z  = hsig(ld_sys(xr_ + u) + s[0] + bias1[u]);
            float r  = hsig(ld_sys(xr_ + UU + u) + s[1] + bias1[UU + u]);
            float hh = tanhf(ld_sys(xr_ + 2 * UU + u) + r * (s[2] + bias1[2 * UU + u]));
            float hold = ld_sys(&hT[(size_t)u * BB + row]);
            st_sys(&h1aT[(size_t)u * BB + row], z * hold + (1.f - z) * hh);
            st_sys(&prl[(size_t)row * UU + u],
                   ld_sys(xr_ + 3 * UU + u) + s[3] + bias1[3 * UU + u]);
        }
        gbar(cnt, phase);

        // ---- T0: tg = h1a @ tkp0 ; gates -> h1b ; plus xg(t+1) ----
        {
            float s[4]; int row, u;
            rt_gemm(h1aT, tkp0, bm, bn, tid, As, Ws, RedF, s, row, u);
            float zt = hsig(s[0] + tb0[u]);
            float rt = hsig(s[1] + tb0[UU + u]);
            float ht = tanhf(rt * (s[2] + tb0[2 * UU + u]));
            float h1v = ld_sys(&h1aT[(size_t)u * BB + row]);
            st_sys(&h1bT[(size_t)u * BB + row], zt * h1v + (1.f - zt) * ht);
        }
        if (t + 1 < TT)
            xg_phase(x, Wxg, bias0, xgn, t + 1, bm, bnx, tid, As, Ws, RedF);
        gbar(cnt, phase);

        // ---- T1 (final): tg = h1b @ tkp1 ; gates + output gate -> h, out ----
        {
            float s[4]; int row, u;
            rt_gemm(h1bT, tkp1, bm, bn, tid, As, Ws, RedF, s, row, u);
            float zt = hsig(s[0] + tb1[u]);
            float rt = hsig(s[1] + tb1[UU + u]);
            float ht = tanhf(rt * (s[2] + tb1[2 * UU + u]));
            float h1v = ld_sys(&h1bT[(size_t)u * BB + row]);
            float h2 = zt * h1v + (1.f - zt) * ht;
            float l = hsig(ld_sys(&prl[(size_t)row * UU + u]));
            float xl2 = ld_sys(&xgc[(size_t)row * G5 + 4 * UU + u]);
            float ho = l * h2 + (1.f - l) * tanhf(xl2);
            st_sys(&hT[(size_t)u * BB + row], ho);
            out[((size_t)row * TT + t) * UU + u] = ho;   // host-read only
        }
        gbar(cnt, phase);

        float* tmp = xgc; xgc = xgn; xgn = tmp;
    }
}

extern "C" void kernel_launch(void* const* d_in, const int* in_sizes, int n_in,
                              void* d_out, int out_size, void* d_ws, size_t ws_size,
                              hipStream_t stream) {
    const float* x      = (const float*)d_in[0];  // (B,T,D)
    const float* h0     = (const float*)d_in[1];  // (B,U)
    const float* kernel = (const float*)d_in[2];  // (D,5U)
    const float* rk     = (const float*)d_in[3];  // (U,4U)
    const float* tk     = (const float*)d_in[4];  // (2,U,3U)
    const float* bias   = (const float*)d_in[5];  // (2,5U)
    const float* tb     = (const float*)d_in[6];  // (2,3U)
    float* out = (float*)d_out;

    // workspace layout (floats); barrier counters occupy first 1024 B
    unsigned* bar = (unsigned*)d_ws;
    float* base = (float*)d_ws + 256;
    float* rkp  = base;                               // 512*2048
    float* tkp0 = rkp  + (size_t)UU * G4;             // 512*2048
    float* tkp1 = tkp0 + (size_t)UU * G4;             // 512*2048
    float* hT   = tkp1 + (size_t)UU * G4;             // U*B (transposed state)
    float* h1aT = hT   + (size_t)BB * UU;
    float* h1bT = h1aT + (size_t)BB * UU;
    float* prl  = h1bT + (size_t)BB * UU;
    float* xg0  = prl  + (size_t)BB * UU;             // B*5U
    float* xg1  = xg0  + (size_t)BB * G5;             // B*5U

    hipMemsetAsync(d_ws, 0, 1024, stream);   // zero barrier counters
    pack_weights<<<dim3((UU * G4) / 256), dim3(256), 0, stream>>>(rk, tk, rkp, tkp0, tkp1);
    init_hT<<<dim3((BB * UU) / 256), dim3(256), 0, stream>>>(h0, hT);

    // Plain launch (graph-capture safe). Residency by capacity: ~69KB LDS
    // -> <=2 blocks/CU, 256 blocks <= 256 CUs -> all co-resident.
    scan_all<<<dim3(NBLK), dim3(512), 0, stream>>>(
        x, kernel, rkp, tkp0, tkp1, bias, tb,
        hT, h1aT, h1bT, prl, xg0, xg1, out, bar);
}